// Round 10
// baseline (414.590 us; speedup 1.0000x reference)
//
#include <hip/hip_runtime.h>
#include <cstdint>
#include <cstddef>

// Problem constants (B,T,C,H,D) = (4,2048,1024,16,64)
#define Bz 4
#define Tz 2048
#define Cz 1024
#define Hz 16
#define Dz 64
#define NTOK (Bz*Tz)   // 8192 tokens
#define CHL 32         // chunk length
#define NCH (Tz/CHL)   // 64 chunks per chain

typedef __attribute__((ext_vector_type(8))) short  short8;   // 8 x bf16 (4 VGPRs)
typedef __attribute__((ext_vector_type(4))) float  floatx4;  // MFMA accum

__device__ __forceinline__ unsigned short f2bf(float x) {
  union { float f; uint32_t u; } a; a.f = x;
  uint32_t r = a.u + 0x7fffu + ((a.u >> 16) & 1u);
  return (unsigned short)(r >> 16);
}
__device__ __forceinline__ float bf2f(unsigned short u) {
  union { uint32_t i; float f; } a; a.i = ((uint32_t)u) << 16; return a.f;
}
__device__ __forceinline__ float sigmoidf_(float z) {
  return 1.0f / (1.0f + __expf(-z));
}
// packed fp32x2 -> bf16x2 (RTNE), one instruction
__device__ __forceinline__ uint32_t cvtpk_bf16(float a, float b) {
  uint32_t d;
  asm volatile("v_cvt_pk_bf16_f32 %0, %1, %2" : "=v"(d) : "v"(a), "v"(b));
  return d;
}
__device__ __forceinline__ float lo16f(uint32_t u) {
  union { uint32_t i; float f; } a; a.i = u << 16; return a.f;
}
__device__ __forceinline__ float hi16f(uint32_t u) {
  union { uint32_t i; float f; } a; a.i = u & 0xffff0000u; return a.f;
}

// async global->LDS DMA (dest = wave-uniform LDS base + lane*16B)
__device__ __forceinline__ void gload_lds16(const void* gptr, void* lptr) {
  __builtin_amdgcn_global_load_lds(
      (const __attribute__((address_space(1))) void*)(uintptr_t)gptr,
      (__attribute__((address_space(3))) void*)(uint32_t)(uintptr_t)lptr,
      16, 0, 0);
}

// ---- DPP 16-lane row reduction ----
template<int CTRL>
__device__ __forceinline__ float dpp_addf(float x) {
  int y = __builtin_amdgcn_update_dpp(0, __float_as_int(x), CTRL, 0xF, 0xF, true);
  return x + __int_as_float(y);
}
__device__ __forceinline__ float rowsum16(float x) {
  x = dpp_addf<0xB1>(x);   // quad_perm xor1
  x = dpp_addf<0x4E>(x);   // quad_perm xor2
  x = dpp_addf<0x124>(x);  // row_ror:4
  x = dpp_addf<0x128>(x);  // row_ror:8
  return x;
}

union FragU { uint32_t u[4]; short8 s; };

// ---------------- fp32 -> bf16 converts (x + 5 weights, one launch) ----------------
__global__ __launch_bounds__(256) void cvt6_kernel(
    const float* __restrict__ s0, const float* __restrict__ s1,
    const float* __restrict__ s2, const float* __restrict__ s3,
    const float* __restrict__ s4, const float* __restrict__ s5,
    unsigned short* __restrict__ d0, unsigned short* __restrict__ d1,
    unsigned short* __restrict__ d2, unsigned short* __restrict__ d3,
    unsigned short* __restrict__ d4, unsigned short* __restrict__ d5,
    int n4x, int n4w)
{
  const int w = blockIdx.y;
  const float* s = (w == 0) ? s0 : (w == 1) ? s1 : (w == 2) ? s2 : (w == 3) ? s3 : (w == 4) ? s4 : s5;
  unsigned short* d = (w == 0) ? d0 : (w == 1) ? d1 : (w == 2) ? d2 : (w == 3) ? d3 : (w == 4) ? d4 : d5;
  const int n4 = (w == 0) ? n4x : n4w;
  int i = blockIdx.x * blockDim.x + threadIdx.x;
  int stride = gridDim.x * blockDim.x;
  const float4* in4 = (const float4*)s;
  ushort4* out4 = (ushort4*)d;
  for (; i < n4; i += stride) {
    float4 f = in4[i];
    ushort4 u;
    u.x = f2bf(f.x); u.y = f2bf(f.y); u.z = f2bf(f.z); u.w = f2bf(f.w);
    out4[i] = u;
  }
}

// ======== 256xBN-tile, BK=64, 8-wave, 8-phase bf16 MFMA GEMM ========
#define VM8()  asm volatile("s_waitcnt vmcnt(8)" ::: "memory")
#define VM6()  asm volatile("s_waitcnt vmcnt(6)" ::: "memory")
#define VM4()  asm volatile("s_waitcnt vmcnt(4)" ::: "memory")
#define VM3()  asm volatile("s_waitcnt vmcnt(3)" ::: "memory")
#define VM0()  asm volatile("s_waitcnt vmcnt(0)" ::: "memory")
#define LGKM0() asm volatile("s_waitcnt lgkmcnt(0)" ::: "memory")
#define BARR() __builtin_amdgcn_s_barrier()

// C[m,n] = sum_k A[m,k]*B[n,k]; B stored [N][K].
// BN: 256 (qkvg, bf16 out) or 128 (out-proj, fp32 out). Direct scattered
// epilogue stores (R3/R5-proven: stores are fire-and-forget; L2 write-combines).
template<int BN, int OB16>
__global__ __launch_bounds__(512, 2) void gemm256_kernel(
    const unsigned short* __restrict__ A,
    const unsigned short* __restrict__ W0, const unsigned short* __restrict__ W1,
    const unsigned short* __restrict__ W2, const unsigned short* __restrict__ W3,
    void* __restrict__ O0, void* __restrict__ O1,
    void* __restrict__ O2, void* __restrict__ O3,
    int M, int N, int K, int nz_sigmoid, int norm_mask)
{
  constexpr int LB  = (BN == 256) ? 2 : 1;   // gloads per B-half per wave
  constexpr int NJ  = BN / 64;               // B j-fragments per wave
  constexpr int AH  = 8192;                  // A half-tile shorts (256x32)
  constexpr int BH  = BN * 32;               // B half-tile shorts
  constexpr int PAR = 2 * AH + 2 * BH;       // shorts per tile-parity
  __shared__ unsigned short smem[2 * PAR];

  // ---- bijective XCD-chunked block swizzle over flattened grid ----
  const int gx = gridDim.x, gz = gridDim.z;
  const int nwg = gx * gridDim.y * gz;
  int flat = (blockIdx.z * gridDim.y + blockIdx.y) * gx + blockIdx.x;
  if ((nwg & 7) == 0) flat = (flat & 7) * (nwg >> 3) + (flat >> 3);
  const int xz = gx * gz;
  const int by = flat / xz;
  const int rem = flat - by * xz;
  const int bz = rem / gx;
  const int bx = rem - bz * gx;

  const unsigned short* Bw = (bz == 0) ? W0 : (bz == 1) ? W1 : (bz == 2) ? W2 : W3;
  void* Cw = (bz == 0) ? O0 : (bz == 1) ? O1 : (bz == 2) ? O2 : O3;
  const bool act = (bz == nz_sigmoid);
  const bool donorm = (norm_mask >> bz) & 1;

  const int m0 = by * 256, n0 = bx * BN;
  const int tid = threadIdx.x;
  const int wid = tid >> 6, lane = tid & 63;
  const int wm = wid >> 2, wn = wid & 3;      // waves: 2M x 4N; per-wave C = 128 x BN/4
  const int ml = lane & 15, kq = lane >> 4;

  const unsigned short* Ap = A  + (size_t)m0 * K;
  const unsigned short* Bp = Bw + (size_t)n0 * K;

  const int srow = wid * 16 + (lane >> 2);
  const int ss8  = ((lane & 3) ^ ((lane >> 3) & 3)) * 8;   // pre-swizzled src slot
  const int rs8  = (kq ^ ((ml >> 1) & 3)) * 8;             // swizzled read slot
  const int arow = wm * 128 + ml;
  const int brow = wn * (BN / 4) + ml;

  const int NT = K >> 6;
  const int hmax = NT << 2;

  floatx4 acc[8][NJ];
#pragma unroll
  for (int i = 0; i < 8; ++i)
#pragma unroll
    for (int j = 0; j < NJ; ++j) acc[i][j] = floatx4{0.f, 0.f, 0.f, 0.f};

  // half h offsets within a parity: 0=A_k0 1=B_k0 2=A_k1 3=B_k1
#define HOFF(hh) ((hh) == 0 ? 0 : (hh) == 1 ? AH : (hh) == 2 ? AH + BH : 2 * AH + BH)
#define STAGE1(hsi) do {                                                      \
    const int ht_ = (hsi) >> 2, hh_ = (hsi) & 3;                              \
    const bool isB_ = hh_ & 1;                                                \
    const unsigned short* p_ = isB_ ? Bp : Ap;                                \
    const int kb_ = ht_ * 64 + (hh_ >> 1) * 32;                               \
    unsigned short* lb_ = &smem[(ht_ & 1) * PAR + HOFF(hh_) + wid * 512];     \
    gload_lds16(p_ + (size_t)srow * K + kb_ + ss8, lb_);                      \
    if (!isB_ || LB == 2)                                                     \
      gload_lds16(p_ + (size_t)(128 + srow) * K + kb_ + ss8, lb_ + 4096);     \
  } while (0)

  int hs = 0;
  for (; hs < 6 && hs < hmax; ++hs) STAGE1(hs);
  if constexpr (BN == 256) { VM8(); } else { VM6(); }
  BARR();

#define LOAD_A(Hb, mh)                                                        \
  _Pragma("unroll") for (int i = 0; i < 4; ++i)                               \
    af[i] = *(const short8*)&Hb[(arow + (mh) * 64 + i * 16) * 32 + rs8];
#define LOAD_B(Hb)                                                            \
  _Pragma("unroll") for (int j = 0; j < NJ; ++j)                              \
    bf[j] = *(const short8*)&Hb[(brow + j * 16) * 32 + rs8];
#define MFMA_Q(mh)                                                            \
  __builtin_amdgcn_s_setprio(1);                                              \
  _Pragma("unroll") for (int i = 0; i < 4; ++i)                               \
    _Pragma("unroll") for (int j = 0; j < NJ; ++j)                            \
      acc[(mh) * 4 + i][j] = __builtin_amdgcn_mfma_f32_16x16x32_bf16(         \
          af[i], bf[j], acc[(mh) * 4 + i][j], 0, 0, 0);                       \
  __builtin_amdgcn_s_setprio(0);
#define STAGE_NEXT() do { if (hs < hmax) { STAGE1(hs); ++hs; } } while (0)

  short8 af[4], bf[NJ];
  for (int t = 0; t < NT; ++t) {
    const unsigned short* Ah0 = &smem[(t & 1) * PAR + HOFF(0)];
    const unsigned short* Bh0 = &smem[(t & 1) * PAR + HOFF(1)];
    const unsigned short* Ah1 = &smem[(t & 1) * PAR + HOFF(2)];
    const unsigned short* Bh1 = &smem[(t & 1) * PAR + HOFF(3)];

    LOAD_A(Ah0, 0); LOAD_B(Bh0);
    STAGE_NEXT();
    BARR(); LGKM0();
    MFMA_Q(0);
    BARR();

    LOAD_A(Ah0, 1);
    STAGE_NEXT();
    BARR(); LGKM0();
    MFMA_Q(1);
    if (t == NT - 1) { VM0(); }
    else { if constexpr (BN == 256) { VM8(); } else { VM6(); } }
    BARR();

    LOAD_A(Ah1, 0); LOAD_B(Bh1);
    STAGE_NEXT();
    BARR(); LGKM0();
    MFMA_Q(0);
    BARR();

    LOAD_A(Ah1, 1);
    STAGE_NEXT();
    BARR(); LGKM0();
    MFMA_Q(1);
    if (t < NT - 2) { if constexpr (BN == 256) { VM8(); } else { VM6(); } }
    else if (t == NT - 2) { if constexpr (BN == 256) { VM4(); } else { VM3(); } }
    BARR();
  }

  float scale[8][4];
  if (donorm) {
#pragma unroll
    for (int i = 0; i < 8; ++i) {
#pragma unroll
      for (int r = 0; r < 4; ++r) {
        float ss = 0.f;
#pragma unroll
        for (int j = 0; j < NJ; ++j) ss = fmaf(acc[i][j][r], acc[i][j][r], ss);
        ss = rowsum16(ss);
        scale[i][r] = 1.0f / fmaxf(sqrtf(ss), 1e-12f);
      }
    }
  }

  // ---- direct epilogue stores (fire-and-forget; L2 write-combines) ----
  const int row_base = m0 + wm * 128;
  const int col_base = n0 + wn * (BN / 4);
#pragma unroll
  for (int i = 0; i < 8; ++i) {
#pragma unroll
    for (int j = 0; j < NJ; ++j) {
      const int col = col_base + j * 16 + ml;
#pragma unroll
      for (int r = 0; r < 4; ++r) {
        const int row = row_base + i * 16 + kq * 4 + r;
        float val = acc[i][j][r];
        if (donorm) val *= scale[i][r];
        if (act) val = sigmoidf_(val);
        if constexpr (OB16) ((unsigned short*)Cw)[(size_t)row * N + col] = f2bf(val);
        else                ((float*)Cw)[(size_t)row * N + col] = val;
      }
    }
  }
}

// ---------------- beta projection (fp32, exact) ----------------
__global__ __launch_bounds__(256) void beta_kernel(
    const float* __restrict__ x, const float* __restrict__ Wb,
    const float* __restrict__ bb, float* __restrict__ beta_out)
{
  const int n = blockIdx.x;
  const int wid = threadIdx.x >> 6;
  const int lane = threadIdx.x & 63;
  const float* xr = x + (size_t)n * Cz;
  for (int h = wid; h < Hz; h += 4) {
    const float* wr = Wb + (size_t)h * Cz;
    float s = 0.f;
#pragma unroll 4
    for (int i = lane; i < Cz; i += 64) s = fmaf(xr[i], wr[i], s);
#pragma unroll
    for (int ofs = 32; ofs >= 1; ofs >>= 1) s += __shfl_xor(s, ofs);
    if (lane == 0) beta_out[(size_t)n * Hz + h] = sigmoidf_(s + bb[h]);
  }
}

// ======== Chunked delta rule ========
__global__ __launch_bounds__(256) void deltachunk_phase1(
    const unsigned short* __restrict__ qb, const unsigned short* __restrict__ kb,
    const unsigned short* __restrict__ vb, const float* __restrict__ betaf,
    float* __restrict__ of,
    unsigned short* __restrict__ qtb, unsigned short* __restrict__ wbuf,
    unsigned short* __restrict__ ubuf, unsigned short* __restrict__ ktb)
{
  __shared__ unsigned short Kb[32][72], Qb[32][72], Vb[32][72];
  __shared__ float As[32][36];       // TRANSPOSED: As[t][s] = coef(s,t); row 16B-aligned
  __shared__ unsigned short Sb[32][40];
  __shared__ unsigned short Us[32][72], Ws[32][72], Qts[32][72];
  __shared__ float bsh[32];

  const int bid = blockIdx.x;
  const int chain = bid & 63;          // chunk-major dispatch for L2 locality
  const int chunk = bid >> 6;
  const int b = chain >> 4, h = chain & 15;
  const int tid = threadIdx.x;
  const int wid = tid >> 6, lane = tid & 63;
  const int ml = lane & 15, kq = lane >> 4;

  const size_t tok0 = (size_t)b * Tz + (size_t)chunk * CHL;
  const size_t cb = ((size_t)chain * NCH + chunk) * 2048;  // compact base (u16)

  // ---- stage chunk: 32x64 bf16 x3, one uint4 per thread per array ----
  {
    const int row = tid >> 3, c8 = (tid & 7) * 8;
    const size_t ga = (tok0 + row) * Cz + h * Dz + c8;
    *(uint4*)&Qb[row][c8] = *(const uint4*)&qb[ga];
    *(uint4*)&Kb[row][c8] = *(const uint4*)&kb[ga];
    *(uint4*)&Vb[row][c8] = *(const uint4*)&vb[ga];
  }
  if (tid < 32) bsh[tid] = betaf[(tok0 + tid) * Hz + h];
  __syncthreads();

  // ---- A = K K^T, S = Q K^T (wave w -> tile (w&1, w>>1)) ----
  {
    const int tr = wid & 1, tc = wid >> 1;
    floatx4 accA = {0.f,0.f,0.f,0.f}, accS = {0.f,0.f,0.f,0.f};
#pragma unroll
    for (int eh = 0; eh < 2; ++eh) {
      short8 ka = *(const short8*)&Kb[tr * 16 + ml][eh * 32 + kq * 8];
      short8 kbf = *(const short8*)&Kb[tc * 16 + ml][eh * 32 + kq * 8];
      short8 qa = *(const short8*)&Qb[tr * 16 + ml][eh * 32 + kq * 8];
      accA = __builtin_amdgcn_mfma_f32_16x16x32_bf16(ka, kbf, accA, 0, 0, 0);
      accS = __builtin_amdgcn_mfma_f32_16x16x32_bf16(qa, kbf, accS, 0, 0, 0);
    }
#pragma unroll
    for (int r = 0; r < 4; ++r) {
      int t = tr * 16 + kq * 4 + r;
      int s = tc * 16 + ml;
      As[s][t] = bsh[t] * accA[r];   // transposed store: As[t'][s'] = coef(s',t')
      Sb[t][s] = (t > s) ? f2bf(accS[r]) : (unsigned short)0;
    }
  }
  __syncthreads();

  // ---- forward substitution: threads 0..127 = columns of [V|K], fp32 ----
  if (tid < 128) {
    const int j = tid;
    float x[32];
    if (j < 64) {
#pragma unroll
      for (int t = 0; t < 32; ++t) x[t] = bsh[t] * bf2f(Vb[t][j]);
    } else {
#pragma unroll
      for (int t = 0; t < 32; ++t) x[t] = bsh[t] * bf2f(Kb[t][j - 64]);
    }
#pragma unroll
    for (int t = 0; t < 31; ++t) {
      float xt = x[t];
#pragma unroll
      for (int s = t + 1; s < 32; ++s) x[s] = fmaf(-As[t][s], xt, x[s]);
    }
    if (j < 64) {
#pragma unroll
      for (int t = 0; t < 32; ++t) Us[t][j] = f2bf(x[t]);
    } else {
#pragma unroll
      for (int t = 0; t < 32; ++t) Ws[t][j - 64] = f2bf(x[t]);
    }
  }
  __syncthreads();

  // ---- O_loc = S_- U -> of ; Qt = Q - S_- W -> Qts (wave w: d cols w*16..) ----
  {
    const int dw = wid * 16 + ml;
    FragU bu, bw;
#pragma unroll
    for (int r = 0; r < 4; ++r) {
      bu.u[r] = (uint32_t)Us[kq * 8 + 2 * r][dw] | ((uint32_t)Us[kq * 8 + 2 * r + 1][dw] << 16);
      bw.u[r] = (uint32_t)Ws[kq * 8 + 2 * r][dw] | ((uint32_t)Ws[kq * 8 + 2 * r + 1][dw] << 16);
    }
    floatx4 accO[2], accQ[2];
#pragma unroll
    for (int tt = 0; tt < 2; ++tt) { accO[tt] = floatx4{0.f,0.f,0.f,0.f}; accQ[tt] = floatx4{0.f,0.f,0.f,0.f}; }
#pragma unroll
    for (int tt = 0; tt < 2; ++tt) {
      short8 sa = *(const short8*)&Sb[tt * 16 + ml][kq * 8];
      accO[tt] = __builtin_amdgcn_mfma_f32_16x16x32_bf16(sa, bu.s, accO[tt], 0, 0, 0);
      accQ[tt] = __builtin_amdgcn_mfma_f32_16x16x32_bf16(sa, bw.s, accQ[tt], 0, 0, 0);
    }
#pragma unroll
    for (int tt = 0; tt < 2; ++tt) {
#pragma unroll
      for (int r = 0; r < 4; ++r) {
        int t = tt * 16 + kq * 4 + r;
        of[(tok0 + t) * Cz + h * Dz + dw] = accO[tt][r];
        Qts[t][dw] = f2bf(bf2f(Qb[t][dw]) - accQ[tt][r]);
      }
    }
  }

  // ---- K^T / U^T gathers (independent of Qts; before barrier) ----
  unsigned short ktmp[8], utmp[8];
  {
    const int e = tid >> 2, tq = (tid & 3) * 8;
#pragma unroll
    for (int i2 = 0; i2 < 8; ++i2) { ktmp[i2] = Kb[tq + i2][e]; utmp[i2] = Us[tq + i2][e]; }
  }
  __syncthreads();

  // ---- compact coalesced stores ----
  {
    const int row = tid >> 3, c8 = (tid & 7) * 8;
    const size_t o16 = cb + (size_t)row * 64 + c8;
    *(uint4*)&qtb[o16]  = *(const uint4*)&Qts[row][c8];
    *(uint4*)&wbuf[o16] = *(const uint4*)&Ws[row][c8];
    const int e = tid >> 2, tq = (tid & 3) * 8;
    *(uint4*)&ktb[cb + (size_t)e * 32 + tq]  = *(const uint4*)ktmp;
    *(uint4*)&ubuf[cb + (size_t)e * 32 + tq] = *(const uint4*)utmp;
  }
}

// Phase 2 (best-measured config): 128 blocks = (chain, d-half), 256 threads;
// fused gate: iq0 waves store ab = bf16(gate*(of + o2)) directly.
__global__ __launch_bounds__(256) void deltachunk_phase2(
    const unsigned short* __restrict__ qtb, const unsigned short* __restrict__ wbuf,
    const unsigned short* __restrict__ ubuf, const unsigned short* __restrict__ ktb,
    const unsigned short* __restrict__ gbuf, const float* __restrict__ ofv,
    unsigned short* __restrict__ ab)
{
  __shared__ unsigned short Gb[2][64][72];    // rows 0..31 Qt, 32..63 W  [i][e]
  __shared__ unsigned short Ub[2][32][40];    // U^T slice [d_local][t]
  __shared__ unsigned short Kts[2][64][40];   // K^T [e][t]
  __shared__ unsigned short Mh[2][32][72], Ml[2][32][72];  // M [d_local][e] ping-pong

  const int chain = blockIdx.x >> 1;
  const int dh = blockIdx.x & 1;             // d-half of the head dim
  const int b = chain >> 4, h = chain & 15;
  const int d0 = dh * 32;
  const int tid = threadIdx.x;
  const int wid = tid >> 6, lane = tid & 63;
  const int ml = lane & 15, kq = lane >> 4;
  const int iq = wid >> 1, jq = wid & 1;     // iq: 0=Qt rows, 1=W rows; jq: d-sub16

  const size_t cbase = (size_t)chain * NCH * 2048;
  const int gcol = h * Dz + d0 + jq * 16 + ml;   // global col for o/gate/ab

  // staging coords (all 256 threads)
  const int grow = tid >> 2;           // 0..63
  const int gc16 = (tid & 3) * 16;     // 16 shorts = 2x uint4
  const int ke   = tid >> 2;           // 0..63
  const int kc8  = (tid & 3) * 8;      // uint4
  const int ue   = tid >> 3;           // 0..31
  const int uc4  = (tid & 7) * 4;      // uint2

  const unsigned short* gsrc = (grow < 32) ? qtb : wbuf;
  const size_t gsoff = (size_t)(grow & 31) * 64 + gc16;

  // prologue: stage chunk 0 into buffer 0; zero M buffer 0; prefetch gate/of(c=0)
  unsigned short pg[8]; float pf[8];
  {
    *(uint4*)&Gb[0][grow][gc16]     = *(const uint4*)&gsrc[cbase + gsoff];
    *(uint4*)&Gb[0][grow][gc16 + 8] = *(const uint4*)&gsrc[cbase + gsoff + 8];
    *(uint4*)&Kts[0][ke][kc8]       = *(const uint4*)&ktb[cbase + (size_t)ke * 32 + kc8];
    *(uint2*)&Ub[0][ue][uc4]        = *(const uint2*)&ubuf[cbase + (size_t)(d0 + ue) * 32 + uc4];
  }
  if (iq == 0) {
    const size_t t0 = (size_t)b * Tz;
#pragma unroll
    for (int ti = 0; ti < 2; ++ti)
#pragma unroll
      for (int r = 0; r < 4; ++r) {
        const size_t gi = (t0 + ti * 16 + kq * 4 + r) * Cz + gcol;
        pg[ti * 4 + r] = gbuf[gi];
        pf[ti * 4 + r] = ofv[gi];
      }
  }
  for (int i = tid; i < 32 * 72; i += 256) { (&Mh[0][0][0])[i] = 0; (&Ml[0][0][0])[i] = 0; }
  __syncthreads();

  // bpermute lane indices for the Z/C transpose
  const int idxA = (ml + 16 * ((kq & 1) * 2)) * 4;
  const int idxB = (ml + 16 * ((kq & 1) * 2 + 1)) * 4;
  const bool hiKq = (kq >= 2);

  floatx4 mAcc[4];
#pragma unroll
  for (int a = 0; a < 4; ++a) mAcc[a] = floatx4{0.f, 0.f, 0.f, 0.f};

  for (int c = 0; c < NCH; ++c) {
    const int cbuf = c & 1, nbuf = cbuf ^ 1;   // staging ping-pong
    const int mr = c & 1, mw = mr ^ 1;         // M ping-pong
    const size_t tok0 = (size_t)b * Tz + (size_t)c * CHL;

    // issue next-chunk global loads (stay in flight across raw barrier)
    const int cn = (c + 1 < NCH) ? c + 1 : c;
    const size_t cbn = cbase + (size_t)cn * 2048;
    uint4 sg0 = *(const uint4*)&gsrc[cbn + gsoff];
    uint4 sg1 = *(const uint4*)&gsrc[cbn + gsoff + 8];
    uint4 sk  = *(const uint4*)&ktb[cbn + (size_t)ke * 32 + kc8];
    uint2 su  = *(const uint2*)&ubuf[cbn + (size_t)(d0 + ue) * 32 + uc4];
    unsigned short ng[8]; float nf[8];
    if (iq == 0) {
      const size_t tkn = (size_t)b * Tz + (size_t)cn * CHL;
#pragma unroll
      for (int ti = 0; ti < 2; ++ti)
#pragma unroll
        for (int r = 0; r < 4; ++r) {
          const size_t gi = (tkn + ti * 16 + kq * 4 + r) * Cz + gcol;
          ng[ti * 4 + r] = gbuf[gi];
          nf[ti * 4 + r] = ofv[gi];
        }
    }

    // --- GEMM1: rows iq*32.., cols (block d-half, sub jq*16), 8 MFMA ---
    floatx4 g1[2];
    g1[0] = floatx4{0.f,0.f,0.f,0.f}; g1[1] = floatx4{0.f,0.f,0.f,0.f};
#pragma unroll
    for (int eh = 0; eh < 2; ++eh) {
      short8 afr0 = *(const short8*)&Gb[cbuf][iq * 32 + 0  + ml][eh * 32 + kq * 8];
      short8 afr1 = *(const short8*)&Gb[cbuf][iq * 32 + 16 + ml][eh * 32 + kq * 8];
      short8 bh = *(const short8*)&Mh[mr][jq * 16 + ml][eh * 32 + kq * 8];
      short8 bl = *(const short8*)&Ml[mr][jq * 16 + ml][eh * 32 + kq * 8];
      g1[0] = __builtin_amdgcn_mfma_f32_16x16x32_bf16(afr0, bh, g1[0], 0, 0, 0);
      g1[0] = __builtin_amdgcn_mfma_f32_16x16x32_bf16(afr0, bl, g1[0], 0, 0, 0);
      g1[1] = __builtin_amdgcn_mfma_f32_16x16x32_bf16(afr1, bh, g1[1], 0, 0, 0);
      g1[1] = __builtin_amdgcn_mfma_f32_16x16x32_bf16(afr1, bl, g1[1], 0, 0, 0);
    }

    if (iq == 0) {
      // --- Qt rows: fused gate epilogue: ab = bf16(gate*(of + o2)) ---
#pragma unroll
      for (int ti = 0; ti < 2; ++ti)
#pragma unroll
        for (int r = 0; r < 4; ++r) {
          const size_t gi = (tok0 + ti * 16 + kq * 4 + r) * Cz + gcol;
          const float val = bf2f(pg[ti * 4 + r]) * (pf[ti * 4 + r] + g1[ti][r]);
          ab[gi] = f2bf(val);
        }
#pragma unroll
      for (int e = 0; e < 8; ++e) { pg[e] = ng[e]; pf[e] = nf[e]; }
    } else {
      // --- Z = U - g1 (hi/lo bf16, packed along t-pairs) ---
      uint32_t pkh[2][2], pkl[2][2];   // [ti][rpair]
#pragma unroll
      for (int ti = 0; ti < 2; ++ti) {
        ushort4 uu = *(const ushort4*)&Ub[cbuf][jq * 16 + ml][ti * 16 + kq * 4];
        float z0 = bf2f(uu.x) - g1[ti][0];
        float z1 = bf2f(uu.y) - g1[ti][1];
        float z2 = bf2f(uu.z) - g1[ti][2];
        float z3 = bf2f(uu.w) - g1[ti][3];
        uint32_t h01 = cvtpk_bf16(z0, z1), h23 = cvtpk_bf16(z2, z3);
        pkh[ti][0] = h01; pkh[ti][1] = h23;
        pkl[ti][0] = cvtpk_bf16(z0 - lo16f(h01), z1 - hi16f(h01));
        pkl[ti][1] = cvtpk_bf16(z2 - lo16f(h23), z3 - hi16f(h23));
      }
      // --- in-register transpose to B-frag (rows d, k=t) ---
      FragU zh, zl;
#pragma unroll
      for (int s = 0; s < 4; ++s) {
        const int idx = (s < 2) ? idxA : idxB;
        const int rp = s & 1;
        int v0 = __builtin_amdgcn_ds_bpermute(idx, (int)pkh[0][rp]);
        int v1 = __builtin_amdgcn_ds_bpermute(idx, (int)pkh[1][rp]);
        zh.u[s] = hiKq ? (uint32_t)v1 : (uint32_t)v0;
        int w0 = __builtin_amdgcn_ds_bpermute(idx, (int)pkl[0][rp]);
        int w1 = __builtin_amdgcn_ds_bpermute(idx, (int)pkl[1][rp]);
        zl.u[s] = hiKq ? (uint32_t)w1 : (uint32_t)w0;
      }
      // --- GEMM2: M'[e][d] += K^T Z (8 MFMA, persistent acc) ---
#pragma unroll
      for (int et = 0; et < 4; ++et) {
        short8 kfr = *(const short8*)&Kts[cbuf][et * 16 + ml][kq * 8];
        mAcc[et] = __builtin_amdgcn_mfma_f32_16x16x32_bf16(kfr, zh.s, mAcc[et], 0, 0, 0);
        mAcc[et] = __builtin_amdgcn_mfma_f32_16x16x32_bf16(kfr, zl.s, mAcc[et], 0, 0, 0);
      }
      // --- M hi/lo transposed write (C[e][d] -> M[d][e]) into buffer mw ---
#pragma unroll
      for (int et = 0; et < 4; ++et) {
        float m0 = mAcc[et][0], m1 = mAcc[et][1], m2 = mAcc[et][2], m3 = mAcc[et][3];
        uint32_t h01 = cvtpk_bf16(m0, m1), h23 = cvtpk_bf16(m2, m3);
        uint32_t l01 = cvtpk_bf16(m0 - lo16f(h01), m1 - hi16f(h01));
        uint32_t l23 = cvtpk_bf16(m2 - lo16f(h23), m3 - hi16f(h23));
        *(uint2*)&Mh[mw][jq * 16 + ml][et * 16 + kq * 4] = make_uint2(h01, h23);
        *(uint2*)&Ml[mw][jq * 16 + ml][et * 16 + kq * 4] = make_uint2(l01, l23);
      }
    }

    // --- commit staged chunk c+1 into buffer nbuf (last read at iter c-1) ---
    *(uint4*)&Gb[nbuf][grow][gc16]     = sg0;
    *(uint4*)&Gb[nbuf][grow][gc16 + 8] = sg1;
    *(uint4*)&Kts[nbuf][ke][kc8]       = sk;
    *(uint2*)&Ub[nbuf][ue][uc4]        = su;

    // raw barrier: drain LDS only; global loads/stores stay in flight
    LGKM0();
    BARR();
  }
}

extern "C" void kernel_launch(void* const* d_in, const int* in_sizes, int n_in,
                              void* d_out, int out_size, void* d_ws, size_t ws_size,
                              hipStream_t stream) {
  const float* x     = (const float*)d_in[0];
  const float* Wq    = (const float*)d_in[1];
  const float* Wk    = (const float*)d_in[2];
  const float* Wv    = (const float*)d_in[3];
  const float* Wbeta = (const float*)d_in[4];
  const float* bbeta = (const float*)d_in[5];
  const float* Wgate = (const float*)d_in[6];
  const float* Wo    = (const float*)d_in[7];
  float* out = (float*)d_out;

  char* ws = (char*)d_ws;
  size_t off = 0;
  auto alloc = [&](size_t bytes) -> char* {
    char* p = ws + off;
    off += (bytes + 255) & ~(size_t)255;
    return p;
  };
  unsigned short* xb  = (unsigned short*)alloc((size_t)NTOK * Cz * 2);
  unsigned short* Wqb = (unsigned short*)alloc((size_t)Cz * Cz * 2);
  unsigned short* Wkb = (unsigned short*)alloc((size_t)Cz * Cz * 2);
  unsigned short* Wvb = (unsigned short*)alloc((size_t)Cz * Cz * 2);
  unsigned short* Wgb = (unsigned short*)alloc((size_t)Cz * Cz * 2);
  unsigned short* Wob = (unsigned short*)alloc((size_t)Cz * Cz * 2);
  unsigned short* qb  = (unsigned short*)alloc((size_t)NTOK * Cz * 2);   // bf16 q (l2normed)
  unsigned short* kb  = (unsigned short*)alloc((size_t)NTOK * Cz * 2);
  unsigned short* vb  = (unsigned short*)alloc((size_t)NTOK * Cz * 2);
  unsigned short* gb  = (unsigned short*)alloc((size_t)NTOK * Cz * 2);   // sigmoid(gate) bf16
  float* of    = (float*)alloc((size_t)NTOK * Cz * 4);
  float* betaf = (float*)alloc((size_t)NTOK * Hz * 4);
  unsigned short* qtb  = (unsigned short*)alloc((size_t)64 * NCH * 2048 * 2);
  unsigned short* wbuf = (unsigned short*)alloc((size_t)64 * NCH * 2048 * 2);
  unsigned short* ubuf = (unsigned short*)alloc((size_t)64 * NCH * 2048 * 2);
  unsigned short* ktb  = (unsigned short*)alloc((size_t)64 * NCH * 2048 * 2);
  unsigned short* ab = xb;  // reuse xb after projection GEMMs

  const int n4x = NTOK * Cz / 4;
  const int n4w = Cz * Cz / 4;

  // all fp32->bf16 converts in one launch (x + 5 weights)
  cvt6_kernel<<<dim3(1024, 6), dim3(256), 0, stream>>>(
      x, Wq, Wk, Wv, Wgate, Wo, xb, Wqb, Wkb, Wvb, Wgb, Wob, n4x, n4w);

  // fused q,k,v,gate projections -> bf16; q,k l2norm epilogue, gate sigmoid
  gemm256_kernel<256, 1><<<dim3(Cz / 256, NTOK / 256, 4), dim3(512), 0, stream>>>(
      xb, Wqb, Wkb, Wvb, Wgb, qb, kb, vb, gb, NTOK, Cz, Cz, 3, 3);

  beta_kernel<<<dim3(NTOK), dim3(256), 0, stream>>>(x, Wbeta, bbeta, betaf);

  deltachunk_phase1<<<dim3(64 * NCH), dim3(256), 0, stream>>>(
      qb, kb, vb, betaf, of, qtb, wbuf, ubuf, ktb);

  // phase2 (128 blocks = chain x d-half, 256 threads), fused gate -> ab
  deltachunk_phase2<<<dim3(128), dim3(256), 0, stream>>>(
      qtb, wbuf, ubuf, ktb, gb, of, ab);

  // out = ab @ Wo^T  (fp32 output) — BN=128: 256 blocks, full GPU
  gemm256_kernel<128, 0><<<dim3(Cz / 128, NTOK / 256, 1), dim3(512), 0, stream>>>(
      ab, Wob, Wob, Wob, Wob, out, out, out, out, NTOK, Cz, Cz, -1, 0);
}

// Round 11
// 366.636 us; speedup vs baseline: 1.1308x; 1.1308x over previous
//
#include <hip/hip_runtime.h>
#include <cstdint>
#include <cstddef>

// Problem constants (B,T,C,H,D) = (4,2048,1024,16,64)
#define Bz 4
#define Tz 2048
#define Cz 1024
#define Hz 16
#define Dz 64
#define NTOK (Bz*Tz)   // 8192 tokens
#define CHL 32         // chunk length
#define NCH (Tz/CHL)   // 64 chunks per chain

typedef __attribute__((ext_vector_type(8))) short  short8;   // 8 x bf16 (4 VGPRs)
typedef __attribute__((ext_vector_type(4))) float  floatx4;  // MFMA accum

__device__ __forceinline__ unsigned short f2bf(float x) {
  union { float f; uint32_t u; } a; a.f = x;
  uint32_t r = a.u + 0x7fffu + ((a.u >> 16) & 1u);
  return (unsigned short)(r >> 16);
}
__device__ __forceinline__ float bf2f(unsigned short u) {
  union { uint32_t i; float f; } a; a.i = ((uint32_t)u) << 16; return a.f;
}
__device__ __forceinline__ float sigmoidf_(float z) {
  return 1.0f / (1.0f + __expf(-z));
}
// packed fp32x2 -> bf16x2 (RTNE), one instruction
__device__ __forceinline__ uint32_t cvtpk_bf16(float a, float b) {
  uint32_t d;
  asm volatile("v_cvt_pk_bf16_f32 %0, %1, %2" : "=v"(d) : "v"(a), "v"(b));
  return d;
}
__device__ __forceinline__ float lo16f(uint32_t u) {
  union { uint32_t i; float f; } a; a.i = u << 16; return a.f;
}
__device__ __forceinline__ float hi16f(uint32_t u) {
  union { uint32_t i; float f; } a; a.i = u & 0xffff0000u; return a.f;
}

// async global->LDS DMA (dest = wave-uniform LDS base + lane*16B)
__device__ __forceinline__ void gload_lds16(const void* gptr, void* lptr) {
  __builtin_amdgcn_global_load_lds(
      (const __attribute__((address_space(1))) void*)(uintptr_t)gptr,
      (__attribute__((address_space(3))) void*)(uint32_t)(uintptr_t)lptr,
      16, 0, 0);
}

// ---- DPP 16-lane row reduction ----
template<int CTRL>
__device__ __forceinline__ float dpp_addf(float x) {
  int y = __builtin_amdgcn_update_dpp(0, __float_as_int(x), CTRL, 0xF, 0xF, true);
  return x + __int_as_float(y);
}
__device__ __forceinline__ float rowsum16(float x) {
  x = dpp_addf<0xB1>(x);   // quad_perm xor1
  x = dpp_addf<0x4E>(x);   // quad_perm xor2
  x = dpp_addf<0x124>(x);  // row_ror:4
  x = dpp_addf<0x128>(x);  // row_ror:8
  return x;
}

union FragU { uint32_t u[4]; short8 s; };

// ---------------- fp32 -> bf16 converts (x + 5 weights, one launch) ----------------
__global__ __launch_bounds__(256) void cvt6_kernel(
    const float* __restrict__ s0, const float* __restrict__ s1,
    const float* __restrict__ s2, const float* __restrict__ s3,
    const float* __restrict__ s4, const float* __restrict__ s5,
    unsigned short* __restrict__ d0, unsigned short* __restrict__ d1,
    unsigned short* __restrict__ d2, unsigned short* __restrict__ d3,
    unsigned short* __restrict__ d4, unsigned short* __restrict__ d5,
    int n4x, int n4w)
{
  const int w = blockIdx.y;
  const float* s = (w == 0) ? s0 : (w == 1) ? s1 : (w == 2) ? s2 : (w == 3) ? s3 : (w == 4) ? s4 : s5;
  unsigned short* d = (w == 0) ? d0 : (w == 1) ? d1 : (w == 2) ? d2 : (w == 3) ? d3 : (w == 4) ? d4 : d5;
  const int n4 = (w == 0) ? n4x : n4w;
  int i = blockIdx.x * blockDim.x + threadIdx.x;
  int stride = gridDim.x * blockDim.x;
  const float4* in4 = (const float4*)s;
  ushort4* out4 = (ushort4*)d;
  for (; i < n4; i += stride) {
    float4 f = in4[i];
    ushort4 u;
    u.x = f2bf(f.x); u.y = f2bf(f.y); u.z = f2bf(f.z); u.w = f2bf(f.w);
    out4[i] = u;
  }
}

// ======== 256xBN-tile, BK=64, 8-wave, 8-phase bf16 MFMA GEMM ========
#define VM8()  asm volatile("s_waitcnt vmcnt(8)" ::: "memory")
#define VM6()  asm volatile("s_waitcnt vmcnt(6)" ::: "memory")
#define VM4()  asm volatile("s_waitcnt vmcnt(4)" ::: "memory")
#define VM3()  asm volatile("s_waitcnt vmcnt(3)" ::: "memory")
#define VM0()  asm volatile("s_waitcnt vmcnt(0)" ::: "memory")
#define LGKM0() asm volatile("s_waitcnt lgkmcnt(0)" ::: "memory")
#define BARR() __builtin_amdgcn_s_barrier()

// C[m,n] = sum_k A[m,k]*B[n,k]; B stored [N][K].
// BN: 256 (qkvg, bf16 out) or 128 (out-proj, fp32 out). Direct scattered
// epilogue stores (R3/R5-proven: stores are fire-and-forget; L2 write-combines).
template<int BN, int OB16>
__global__ __launch_bounds__(512, 2) void gemm256_kernel(
    const unsigned short* __restrict__ A,
    const unsigned short* __restrict__ W0, const unsigned short* __restrict__ W1,
    const unsigned short* __restrict__ W2, const unsigned short* __restrict__ W3,
    void* __restrict__ O0, void* __restrict__ O1,
    void* __restrict__ O2, void* __restrict__ O3,
    int M, int N, int K, int nz_sigmoid, int norm_mask)
{
  constexpr int LB  = (BN == 256) ? 2 : 1;   // gloads per B-half per wave
  constexpr int NJ  = BN / 64;               // B j-fragments per wave
  constexpr int AH  = 8192;                  // A half-tile shorts (256x32)
  constexpr int BH  = BN * 32;               // B half-tile shorts
  constexpr int PAR = 2 * AH + 2 * BH;       // shorts per tile-parity
  __shared__ unsigned short smem[2 * PAR];

  // ---- bijective XCD-chunked block swizzle over flattened grid ----
  const int gx = gridDim.x, gz = gridDim.z;
  const int nwg = gx * gridDim.y * gz;
  int flat = (blockIdx.z * gridDim.y + blockIdx.y) * gx + blockIdx.x;
  if ((nwg & 7) == 0) flat = (flat & 7) * (nwg >> 3) + (flat >> 3);
  const int xz = gx * gz;
  const int by = flat / xz;
  const int rem = flat - by * xz;
  const int bz = rem / gx;
  const int bx = rem - bz * gx;

  const unsigned short* Bw = (bz == 0) ? W0 : (bz == 1) ? W1 : (bz == 2) ? W2 : W3;
  void* Cw = (bz == 0) ? O0 : (bz == 1) ? O1 : (bz == 2) ? O2 : O3;
  const bool act = (bz == nz_sigmoid);
  const bool donorm = (norm_mask >> bz) & 1;

  const int m0 = by * 256, n0 = bx * BN;
  const int tid = threadIdx.x;
  const int wid = tid >> 6, lane = tid & 63;
  const int wm = wid >> 2, wn = wid & 3;      // waves: 2M x 4N; per-wave C = 128 x BN/4
  const int ml = lane & 15, kq = lane >> 4;

  const unsigned short* Ap = A  + (size_t)m0 * K;
  const unsigned short* Bp = Bw + (size_t)n0 * K;

  const int srow = wid * 16 + (lane >> 2);
  const int ss8  = ((lane & 3) ^ ((lane >> 3) & 3)) * 8;   // pre-swizzled src slot
  const int rs8  = (kq ^ ((ml >> 1) & 3)) * 8;             // swizzled read slot
  const int arow = wm * 128 + ml;
  const int brow = wn * (BN / 4) + ml;

  const int NT = K >> 6;
  const int hmax = NT << 2;

  floatx4 acc[8][NJ];
#pragma unroll
  for (int i = 0; i < 8; ++i)
#pragma unroll
    for (int j = 0; j < NJ; ++j) acc[i][j] = floatx4{0.f, 0.f, 0.f, 0.f};

  // half h offsets within a parity: 0=A_k0 1=B_k0 2=A_k1 3=B_k1
#define HOFF(hh) ((hh) == 0 ? 0 : (hh) == 1 ? AH : (hh) == 2 ? AH + BH : 2 * AH + BH)
#define STAGE1(hsi) do {                                                      \
    const int ht_ = (hsi) >> 2, hh_ = (hsi) & 3;                              \
    const bool isB_ = hh_ & 1;                                                \
    const unsigned short* p_ = isB_ ? Bp : Ap;                                \
    const int kb_ = ht_ * 64 + (hh_ >> 1) * 32;                               \
    unsigned short* lb_ = &smem[(ht_ & 1) * PAR + HOFF(hh_) + wid * 512];     \
    gload_lds16(p_ + (size_t)srow * K + kb_ + ss8, lb_);                      \
    if (!isB_ || LB == 2)                                                     \
      gload_lds16(p_ + (size_t)(128 + srow) * K + kb_ + ss8, lb_ + 4096);     \
  } while (0)

  int hs = 0;
  for (; hs < 6 && hs < hmax; ++hs) STAGE1(hs);
  if constexpr (BN == 256) { VM8(); } else { VM6(); }
  BARR();

#define LOAD_A(Hb, mh)                                                        \
  _Pragma("unroll") for (int i = 0; i < 4; ++i)                               \
    af[i] = *(const short8*)&Hb[(arow + (mh) * 64 + i * 16) * 32 + rs8];
#define LOAD_B(Hb)                                                            \
  _Pragma("unroll") for (int j = 0; j < NJ; ++j)                              \
    bf[j] = *(const short8*)&Hb[(brow + j * 16) * 32 + rs8];
#define MFMA_Q(mh)                                                            \
  __builtin_amdgcn_s_setprio(1);                                              \
  _Pragma("unroll") for (int i = 0; i < 4; ++i)                               \
    _Pragma("unroll") for (int j = 0; j < NJ; ++j)                            \
      acc[(mh) * 4 + i][j] = __builtin_amdgcn_mfma_f32_16x16x32_bf16(         \
          af[i], bf[j], acc[(mh) * 4 + i][j], 0, 0, 0);                       \
  __builtin_amdgcn_s_setprio(0);
#define STAGE_NEXT() do { if (hs < hmax) { STAGE1(hs); ++hs; } } while (0)

  short8 af[4], bf[NJ];
  for (int t = 0; t < NT; ++t) {
    const unsigned short* Ah0 = &smem[(t & 1) * PAR + HOFF(0)];
    const unsigned short* Bh0 = &smem[(t & 1) * PAR + HOFF(1)];
    const unsigned short* Ah1 = &smem[(t & 1) * PAR + HOFF(2)];
    const unsigned short* Bh1 = &smem[(t & 1) * PAR + HOFF(3)];

    LOAD_A(Ah0, 0); LOAD_B(Bh0);
    STAGE_NEXT();
    BARR(); LGKM0();
    MFMA_Q(0);
    BARR();

    LOAD_A(Ah0, 1);
    STAGE_NEXT();
    BARR(); LGKM0();
    MFMA_Q(1);
    if (t == NT - 1) { VM0(); }
    else { if constexpr (BN == 256) { VM8(); } else { VM6(); } }
    BARR();

    LOAD_A(Ah1, 0); LOAD_B(Bh1);
    STAGE_NEXT();
    BARR(); LGKM0();
    MFMA_Q(0);
    BARR();

    LOAD_A(Ah1, 1);
    STAGE_NEXT();
    BARR(); LGKM0();
    MFMA_Q(1);
    if (t < NT - 2) { if constexpr (BN == 256) { VM8(); } else { VM6(); } }
    else if (t == NT - 2) { if constexpr (BN == 256) { VM4(); } else { VM3(); } }
    BARR();
  }

  float scale[8][4];
  if (donorm) {
#pragma unroll
    for (int i = 0; i < 8; ++i) {
#pragma unroll
      for (int r = 0; r < 4; ++r) {
        float ss = 0.f;
#pragma unroll
        for (int j = 0; j < NJ; ++j) ss = fmaf(acc[i][j][r], acc[i][j][r], ss);
        ss = rowsum16(ss);
        scale[i][r] = 1.0f / fmaxf(sqrtf(ss), 1e-12f);
      }
    }
  }

  // ---- direct epilogue stores (fire-and-forget; L2 write-combines) ----
  const int row_base = m0 + wm * 128;
  const int col_base = n0 + wn * (BN / 4);
#pragma unroll
  for (int i = 0; i < 8; ++i) {
#pragma unroll
    for (int j = 0; j < NJ; ++j) {
      const int col = col_base + j * 16 + ml;
#pragma unroll
      for (int r = 0; r < 4; ++r) {
        const int row = row_base + i * 16 + kq * 4 + r;
        float val = acc[i][j][r];
        if (donorm) val *= scale[i][r];
        if (act) val = sigmoidf_(val);
        if constexpr (OB16) ((unsigned short*)Cw)[(size_t)row * N + col] = f2bf(val);
        else                ((float*)Cw)[(size_t)row * N + col] = val;
      }
    }
  }
}

// ---------------- beta projection (fp32, exact) ----------------
__global__ __launch_bounds__(256) void beta_kernel(
    const float* __restrict__ x, const float* __restrict__ Wb,
    const float* __restrict__ bb, float* __restrict__ beta_out)
{
  const int n = blockIdx.x;
  const int wid = threadIdx.x >> 6;
  const int lane = threadIdx.x & 63;
  const float* xr = x + (size_t)n * Cz;
  for (int h = wid; h < Hz; h += 4) {
    const float* wr = Wb + (size_t)h * Cz;
    float s = 0.f;
#pragma unroll 4
    for (int i = lane; i < Cz; i += 64) s = fmaf(xr[i], wr[i], s);
#pragma unroll
    for (int ofs = 32; ofs >= 1; ofs >>= 1) s += __shfl_xor(s, ofs);
    if (lane == 0) beta_out[(size_t)n * Hz + h] = sigmoidf_(s + bb[h]);
  }
}

// ======== Chunked delta rule ========
__global__ __launch_bounds__(256) void deltachunk_phase1(
    const unsigned short* __restrict__ qb, const unsigned short* __restrict__ kb,
    const unsigned short* __restrict__ vb, const float* __restrict__ betaf,
    float* __restrict__ of,
    unsigned short* __restrict__ qtb, unsigned short* __restrict__ wbuf,
    unsigned short* __restrict__ ubuf, unsigned short* __restrict__ ktb)
{
  __shared__ unsigned short Kb[32][72], Qb[32][72], Vb[32][72];
  __shared__ float As[32][36];       // TRANSPOSED: As[t][s] = coef(s,t); row 16B-aligned
  __shared__ unsigned short Sb[32][40];
  __shared__ unsigned short Us[32][72], Ws[32][72], Qts[32][72];
  __shared__ float bsh[32];

  const int bid = blockIdx.x;
  const int chain = bid & 63;          // chunk-major dispatch for L2 locality
  const int chunk = bid >> 6;
  const int b = chain >> 4, h = chain & 15;
  const int tid = threadIdx.x;
  const int wid = tid >> 6, lane = tid & 63;
  const int ml = lane & 15, kq = lane >> 4;

  const size_t tok0 = (size_t)b * Tz + (size_t)chunk * CHL;
  const size_t cb = ((size_t)chain * NCH + chunk) * 2048;  // compact base (u16)

  // ---- stage chunk: 32x64 bf16 x3, one uint4 per thread per array ----
  {
    const int row = tid >> 3, c8 = (tid & 7) * 8;
    const size_t ga = (tok0 + row) * Cz + h * Dz + c8;
    *(uint4*)&Qb[row][c8] = *(const uint4*)&qb[ga];
    *(uint4*)&Kb[row][c8] = *(const uint4*)&kb[ga];
    *(uint4*)&Vb[row][c8] = *(const uint4*)&vb[ga];
  }
  if (tid < 32) bsh[tid] = betaf[(tok0 + tid) * Hz + h];
  __syncthreads();

  // ---- A = K K^T, S = Q K^T (wave w -> tile (w&1, w>>1)) ----
  {
    const int tr = wid & 1, tc = wid >> 1;
    floatx4 accA = {0.f,0.f,0.f,0.f}, accS = {0.f,0.f,0.f,0.f};
#pragma unroll
    for (int eh = 0; eh < 2; ++eh) {
      short8 ka = *(const short8*)&Kb[tr * 16 + ml][eh * 32 + kq * 8];
      short8 kbf = *(const short8*)&Kb[tc * 16 + ml][eh * 32 + kq * 8];
      short8 qa = *(const short8*)&Qb[tr * 16 + ml][eh * 32 + kq * 8];
      accA = __builtin_amdgcn_mfma_f32_16x16x32_bf16(ka, kbf, accA, 0, 0, 0);
      accS = __builtin_amdgcn_mfma_f32_16x16x32_bf16(qa, kbf, accS, 0, 0, 0);
    }
#pragma unroll
    for (int r = 0; r < 4; ++r) {
      int t = tr * 16 + kq * 4 + r;
      int s = tc * 16 + ml;
      As[s][t] = bsh[t] * accA[r];   // transposed store: As[t'][s'] = coef(s',t')
      Sb[t][s] = (t > s) ? f2bf(accS[r]) : (unsigned short)0;
    }
  }
  __syncthreads();

  // ---- forward substitution: threads 0..127 = columns of [V|K], fp32 ----
  if (tid < 128) {
    const int j = tid;
    float x[32];
    if (j < 64) {
#pragma unroll
      for (int t = 0; t < 32; ++t) x[t] = bsh[t] * bf2f(Vb[t][j]);
    } else {
#pragma unroll
      for (int t = 0; t < 32; ++t) x[t] = bsh[t] * bf2f(Kb[t][j - 64]);
    }
#pragma unroll
    for (int t = 0; t < 31; ++t) {
      float xt = x[t];
#pragma unroll
      for (int s = t + 1; s < 32; ++s) x[s] = fmaf(-As[t][s], xt, x[s]);
    }
    if (j < 64) {
#pragma unroll
      for (int t = 0; t < 32; ++t) Us[t][j] = f2bf(x[t]);
    } else {
#pragma unroll
      for (int t = 0; t < 32; ++t) Ws[t][j - 64] = f2bf(x[t]);
    }
  }
  __syncthreads();

  // ---- O_loc = S_- U -> of ; Qt = Q - S_- W -> Qts (wave w: d cols w*16..) ----
  {
    const int dw = wid * 16 + ml;
    FragU bu, bw;
#pragma unroll
    for (int r = 0; r < 4; ++r) {
      bu.u[r] = (uint32_t)Us[kq * 8 + 2 * r][dw] | ((uint32_t)Us[kq * 8 + 2 * r + 1][dw] << 16);
      bw.u[r] = (uint32_t)Ws[kq * 8 + 2 * r][dw] | ((uint32_t)Ws[kq * 8 + 2 * r + 1][dw] << 16);
    }
    floatx4 accO[2], accQ[2];
#pragma unroll
    for (int tt = 0; tt < 2; ++tt) { accO[tt] = floatx4{0.f,0.f,0.f,0.f}; accQ[tt] = floatx4{0.f,0.f,0.f,0.f}; }
#pragma unroll
    for (int tt = 0; tt < 2; ++tt) {
      short8 sa = *(const short8*)&Sb[tt * 16 + ml][kq * 8];
      accO[tt] = __builtin_amdgcn_mfma_f32_16x16x32_bf16(sa, bu.s, accO[tt], 0, 0, 0);
      accQ[tt] = __builtin_amdgcn_mfma_f32_16x16x32_bf16(sa, bw.s, accQ[tt], 0, 0, 0);
    }
#pragma unroll
    for (int tt = 0; tt < 2; ++tt) {
#pragma unroll
      for (int r = 0; r < 4; ++r) {
        int t = tt * 16 + kq * 4 + r;
        of[(tok0 + t) * Cz + h * Dz + dw] = accO[tt][r];
        Qts[t][dw] = f2bf(bf2f(Qb[t][dw]) - accQ[tt][r]);
      }
    }
  }

  // ---- K^T / U^T gathers (independent of Qts; before barrier) ----
  unsigned short ktmp[8], utmp[8];
  {
    const int e = tid >> 2, tq = (tid & 3) * 8;
#pragma unroll
    for (int i2 = 0; i2 < 8; ++i2) { ktmp[i2] = Kb[tq + i2][e]; utmp[i2] = Us[tq + i2][e]; }
  }
  __syncthreads();

  // ---- compact coalesced stores ----
  {
    const int row = tid >> 3, c8 = (tid & 7) * 8;
    const size_t o16 = cb + (size_t)row * 64 + c8;
    *(uint4*)&qtb[o16]  = *(const uint4*)&Qts[row][c8];
    *(uint4*)&wbuf[o16] = *(const uint4*)&Ws[row][c8];
    const int e = tid >> 2, tq = (tid & 3) * 8;
    *(uint4*)&ktb[cb + (size_t)e * 32 + tq]  = *(const uint4*)ktmp;
    *(uint4*)&ubuf[cb + (size_t)e * 32 + tq] = *(const uint4*)utmp;
  }
}

// Phase 2 (best-measured config): 128 blocks = (chain, d-half), 256 threads;
// fused gate: iq0 waves store ab = bf16(gate*(of + o2)) directly.
__global__ __launch_bounds__(256) void deltachunk_phase2(
    const unsigned short* __restrict__ qtb, const unsigned short* __restrict__ wbuf,
    const unsigned short* __restrict__ ubuf, const unsigned short* __restrict__ ktb,
    const unsigned short* __restrict__ gbuf, const float* __restrict__ ofv,
    unsigned short* __restrict__ ab)
{
  __shared__ unsigned short Gb[2][64][72];    // rows 0..31 Qt, 32..63 W  [i][e]
  __shared__ unsigned short Ub[2][32][40];    // U^T slice [d_local][t]
  __shared__ unsigned short Kts[2][64][40];   // K^T [e][t]
  __shared__ unsigned short Mh[2][32][72], Ml[2][32][72];  // M [d_local][e] ping-pong

  const int chain = blockIdx.x >> 1;
  const int dh = blockIdx.x & 1;             // d-half of the head dim
  const int b = chain >> 4, h = chain & 15;
  const int d0 = dh * 32;
  const int tid = threadIdx.x;
  const int wid = tid >> 6, lane = tid & 63;
  const int ml = lane & 15, kq = lane >> 4;
  const int iq = wid >> 1, jq = wid & 1;     // iq: 0=Qt rows, 1=W rows; jq: d-sub16

  const size_t cbase = (size_t)chain * NCH * 2048;
  const int gcol = h * Dz + d0 + jq * 16 + ml;   // global col for o/gate/ab

  // staging coords (all 256 threads)
  const int grow = tid >> 2;           // 0..63
  const int gc16 = (tid & 3) * 16;     // 16 shorts = 2x uint4
  const int ke   = tid >> 2;           // 0..63
  const int kc8  = (tid & 3) * 8;      // uint4
  const int ue   = tid >> 3;           // 0..31
  const int uc4  = (tid & 7) * 4;      // uint2

  const unsigned short* gsrc = (grow < 32) ? qtb : wbuf;
  const size_t gsoff = (size_t)(grow & 31) * 64 + gc16;

  // prologue: stage chunk 0 into buffer 0; zero M buffer 0; prefetch gate/of(c=0)
  unsigned short pg[8]; float pf[8];
  {
    *(uint4*)&Gb[0][grow][gc16]     = *(const uint4*)&gsrc[cbase + gsoff];
    *(uint4*)&Gb[0][grow][gc16 + 8] = *(const uint4*)&gsrc[cbase + gsoff + 8];
    *(uint4*)&Kts[0][ke][kc8]       = *(const uint4*)&ktb[cbase + (size_t)ke * 32 + kc8];
    *(uint2*)&Ub[0][ue][uc4]        = *(const uint2*)&ubuf[cbase + (size_t)(d0 + ue) * 32 + uc4];
  }
  if (iq == 0) {
    const size_t t0 = (size_t)b * Tz;
#pragma unroll
    for (int ti = 0; ti < 2; ++ti)
#pragma unroll
      for (int r = 0; r < 4; ++r) {
        const size_t gi = (t0 + ti * 16 + kq * 4 + r) * Cz + gcol;
        pg[ti * 4 + r] = gbuf[gi];
        pf[ti * 4 + r] = ofv[gi];
      }
  }
  for (int i = tid; i < 32 * 72; i += 256) { (&Mh[0][0][0])[i] = 0; (&Ml[0][0][0])[i] = 0; }
  __syncthreads();

  // bpermute lane indices for the Z/C transpose
  const int idxA = (ml + 16 * ((kq & 1) * 2)) * 4;
  const int idxB = (ml + 16 * ((kq & 1) * 2 + 1)) * 4;
  const bool hiKq = (kq >= 2);

  floatx4 mAcc[4];
#pragma unroll
  for (int a = 0; a < 4; ++a) mAcc[a] = floatx4{0.f, 0.f, 0.f, 0.f};

  for (int c = 0; c < NCH; ++c) {
    const int cbuf = c & 1, nbuf = cbuf ^ 1;   // staging ping-pong
    const int mr = c & 1, mw = mr ^ 1;         // M ping-pong
    const size_t tok0 = (size_t)b * Tz + (size_t)c * CHL;

    // issue next-chunk global loads (stay in flight across raw barrier)
    const int cn = (c + 1 < NCH) ? c + 1 : c;
    const size_t cbn = cbase + (size_t)cn * 2048;
    uint4 sg0 = *(const uint4*)&gsrc[cbn + gsoff];
    uint4 sg1 = *(const uint4*)&gsrc[cbn + gsoff + 8];
    uint4 sk  = *(const uint4*)&ktb[cbn + (size_t)ke * 32 + kc8];
    uint2 su  = *(const uint2*)&ubuf[cbn + (size_t)(d0 + ue) * 32 + uc4];
    unsigned short ng[8]; float nf[8];
    if (iq == 0) {
      const size_t tkn = (size_t)b * Tz + (size_t)cn * CHL;
#pragma unroll
      for (int ti = 0; ti < 2; ++ti)
#pragma unroll
        for (int r = 0; r < 4; ++r) {
          const size_t gi = (tkn + ti * 16 + kq * 4 + r) * Cz + gcol;
          ng[ti * 4 + r] = gbuf[gi];
          nf[ti * 4 + r] = ofv[gi];
        }
    }

    // --- GEMM1: rows iq*32.., cols (block d-half, sub jq*16), 8 MFMA ---
    floatx4 g1[2];
    g1[0] = floatx4{0.f,0.f,0.f,0.f}; g1[1] = floatx4{0.f,0.f,0.f,0.f};
#pragma unroll
    for (int eh = 0; eh < 2; ++eh) {
      short8 afr0 = *(const short8*)&Gb[cbuf][iq * 32 + 0  + ml][eh * 32 + kq * 8];
      short8 afr1 = *(const short8*)&Gb[cbuf][iq * 32 + 16 + ml][eh * 32 + kq * 8];
      short8 bh = *(const short8*)&Mh[mr][jq * 16 + ml][eh * 32 + kq * 8];
      short8 bl = *(const short8*)&Ml[mr][jq * 16 + ml][eh * 32 + kq * 8];
      g1[0] = __builtin_amdgcn_mfma_f32_16x16x32_bf16(afr0, bh, g1[0], 0, 0, 0);
      g1[0] = __builtin_amdgcn_mfma_f32_16x16x32_bf16(afr0, bl, g1[0], 0, 0, 0);
      g1[1] = __builtin_amdgcn_mfma_f32_16x16x32_bf16(afr1, bh, g1[1], 0, 0, 0);
      g1[1] = __builtin_amdgcn_mfma_f32_16x16x32_bf16(afr1, bl, g1[1], 0, 0, 0);
    }

    if (iq == 0) {
      // --- Qt rows: fused gate epilogue: ab = bf16(gate*(of + o2)) ---
#pragma unroll
      for (int ti = 0; ti < 2; ++ti)
#pragma unroll
        for (int r = 0; r < 4; ++r) {
          const size_t gi = (tok0 + ti * 16 + kq * 4 + r) * Cz + gcol;
          const float val = bf2f(pg[ti * 4 + r]) * (pf[ti * 4 + r] + g1[ti][r]);
          ab[gi] = f2bf(val);
        }
#pragma unroll
      for (int e = 0; e < 8; ++e) { pg[e] = ng[e]; pf[e] = nf[e]; }
    } else {
      // --- Z = U - g1 (hi/lo bf16, packed along t-pairs) ---
      uint32_t pkh[2][2], pkl[2][2];   // [ti][rpair]
#pragma unroll
      for (int ti = 0; ti < 2; ++ti) {
        ushort4 uu = *(const ushort4*)&Ub[cbuf][jq * 16 + ml][ti * 16 + kq * 4];
        float z0 = bf2f(uu.x) - g1[ti][0];
        float z1 = bf2f(uu.y) - g1[ti][1];
        float z2 = bf2f(uu.z) - g1[ti][2];
        float z3 = bf2f(uu.w) - g1[ti][3];
        uint32_t h01 = cvtpk_bf16(z0, z1), h23 = cvtpk_bf16(z2, z3);
        pkh[ti][0] = h01; pkh[ti][1] = h23;
        pkl[ti][0] = cvtpk_bf16(z0 - lo16f(h01), z1 - hi16f(h01));
        pkl[ti][1] = cvtpk_bf16(z2 - lo16f(h23), z3 - hi16f(h23));
      }
      // --- in-register transpose to B-frag (rows d, k=t) ---
      FragU zh, zl;
#pragma unroll
      for (int s = 0; s < 4; ++s) {
        const int idx = (s < 2) ? idxA : idxB;
        const int rp = s & 1;
        int v0 = __builtin_amdgcn_ds_bpermute(idx, (int)pkh[0][rp]);
        int v1 = __builtin_amdgcn_ds_bpermute(idx, (int)pkh[1][rp]);
        zh.u[s] = hiKq ? (uint32_t)v1 : (uint32_t)v0;
        int w0 = __builtin_amdgcn_ds_bpermute(idx, (int)pkl[0][rp]);
        int w1 = __builtin_amdgcn_ds_bpermute(idx, (int)pkl[1][rp]);
        zl.u[s] = hiKq ? (uint32_t)w1 : (uint32_t)w0;
      }
      // --- GEMM2: M'[e][d] += K^T Z (8 MFMA, persistent acc) ---
#pragma unroll
      for (int et = 0; et < 4; ++et) {
        short8 kfr = *(const short8*)&Kts[cbuf][et * 16 + ml][kq * 8];
        mAcc[et] = __builtin_amdgcn_mfma_f32_16x16x32_bf16(kfr, zh.s, mAcc[et], 0, 0, 0);
        mAcc[et] = __builtin_amdgcn_mfma_f32_16x16x32_bf16(kfr, zl.s, mAcc[et], 0, 0, 0);
      }
      // --- M hi/lo transposed write (C[e][d] -> M[d][e]) into buffer mw ---
#pragma unroll
      for (int et = 0; et < 4; ++et) {
        float m0 = mAcc[et][0], m1 = mAcc[et][1], m2 = mAcc[et][2], m3 = mAcc[et][3];
        uint32_t h01 = cvtpk_bf16(m0, m1), h23 = cvtpk_bf16(m2, m3);
        uint32_t l01 = cvtpk_bf16(m0 - lo16f(h01), m1 - hi16f(h01));
        uint32_t l23 = cvtpk_bf16(m2 - lo16f(h23), m3 - hi16f(h23));
        *(uint2*)&Mh[mw][jq * 16 + ml][et * 16 + kq * 4] = make_uint2(h01, h23);
        *(uint2*)&Ml[mw][jq * 16 + ml][et * 16 + kq * 4] = make_uint2(l01, l23);
      }
    }

    // --- commit staged chunk c+1 into buffer nbuf (last read at iter c-1) ---
    *(uint4*)&Gb[nbuf][grow][gc16]     = sg0;
    *(uint4*)&Gb[nbuf][grow][gc16 + 8] = sg1;
    *(uint4*)&Kts[nbuf][ke][kc8]       = sk;
    *(uint2*)&Ub[nbuf][ue][uc4]        = su;

    // raw barrier: drain LDS only; global loads/stores stay in flight
    LGKM0();
    BARR();
  }
}

extern "C" void kernel_launch(void* const* d_in, const int* in_sizes, int n_in,
                              void* d_out, int out_size, void* d_ws, size_t ws_size,
                              hipStream_t stream) {
  const float* x     = (const float*)d_in[0];
  const float* Wq    = (const float*)d_in[1];
  const float* Wk    = (const float*)d_in[2];
  const float* Wv    = (const float*)d_in[3];
  const float* Wbeta = (const float*)d_in[4];
  const float* bbeta = (const float*)d_in[5];
  const float* Wgate = (const float*)d_in[6];
  const float* Wo    = (const float*)d_in[7];
  float* out = (float*)d_out;

  char* ws = (char*)d_ws;
  size_t off = 0;
  auto alloc = [&](size_t bytes) -> char* {
    char* p = ws + off;
    off += (bytes + 255) & ~(size_t)255;
    return p;
  };
  unsigned short* xb  = (unsigned short*)alloc((size_t)NTOK * Cz * 2);
  unsigned short* Wqb = (unsigned short*)alloc((size_t)Cz * Cz * 2);
  unsigned short* Wkb = (unsigned short*)alloc((size_t)Cz * Cz * 2);
  unsigned short* Wvb = (unsigned short*)alloc((size_t)Cz * Cz * 2);
  unsigned short* Wgb = (unsigned short*)alloc((size_t)Cz * Cz * 2);
  unsigned short* Wob = (unsigned short*)alloc((size_t)Cz * Cz * 2);
  unsigned short* qb  = (unsigned short*)alloc((size_t)NTOK * Cz * 2);   // bf16 q (l2normed)
  unsigned short* kb  = (unsigned short*)alloc((size_t)NTOK * Cz * 2);
  unsigned short* vb  = (unsigned short*)alloc((size_t)NTOK * Cz * 2);
  unsigned short* gb  = (unsigned short*)alloc((size_t)NTOK * Cz * 2);   // sigmoid(gate) bf16
  float* of    = (float*)alloc((size_t)NTOK * Cz * 4);
  float* betaf = (float*)alloc((size_t)NTOK * Hz * 4);
  unsigned short* qtb  = (unsigned short*)alloc((size_t)64 * NCH * 2048 * 2);
  unsigned short* wbuf = (unsigned short*)alloc((size_t)64 * NCH * 2048 * 2);
  unsigned short* ubuf = (unsigned short*)alloc((size_t)64 * NCH * 2048 * 2);
  unsigned short* ktb  = (unsigned short*)alloc((size_t)64 * NCH * 2048 * 2);
  unsigned short* ab = xb;  // reuse xb after projection GEMMs

  const int n4x = NTOK * Cz / 4;
  const int n4w = Cz * Cz / 4;

  // all fp32->bf16 converts in one launch (x + 5 weights)
  cvt6_kernel<<<dim3(1024, 6), dim3(256), 0, stream>>>(
      x, Wq, Wk, Wv, Wgate, Wo, xb, Wqb, Wkb, Wvb, Wgb, Wob, n4x, n4w);

  // fused q,k,v,gate projections -> bf16; q,k l2norm epilogue, gate sigmoid
  gemm256_kernel<256, 1><<<dim3(Cz / 256, NTOK / 256, 4), dim3(512), 0, stream>>>(
      xb, Wqb, Wkb, Wvb, Wgb, qb, kb, vb, gb, NTOK, Cz, Cz, 3, 3);

  beta_kernel<<<dim3(NTOK), dim3(256), 0, stream>>>(x, Wbeta, bbeta, betaf);

  deltachunk_phase1<<<dim3(64 * NCH), dim3(256), 0, stream>>>(
      qb, kb, vb, betaf, of, qtb, wbuf, ubuf, ktb);

  // phase2 (128 blocks = chain x d-half, 256 threads), fused gate -> ab
  deltachunk_phase2<<<dim3(128), dim3(256), 0, stream>>>(
      qtb, wbuf, ubuf, ktb, gb, of, ab);

  // out = ab @ Wo^T  (fp32 output) — BN=128: 256 blocks, full GPU
  gemm256_kernel<128, 0><<<dim3(Cz / 128, NTOK / 256, 1), dim3(512), 0, stream>>>(
      ab, Wob, Wob, Wob, Wob, out, out, out, out, NTOK, Cz, Cz, -1, 0);
}